// Round 2
// baseline (3357.243 us; speedup 1.0000x reference)
//
#include <hip/hip_runtime.h>

// HGNN aggregation: out = x + segment_sum(x[src_idx], dst_idx)
// x: [100000, 128] f32; src_idx/dst_idx: [2,000,000] int32 (harness casts
// integer inputs to int32 regardless of the reference's int64!).
//
// Round 2: atomic baseline, indices fixed to int32.

constexpr int N_NODES = 100000;
constexpr int DIM = 128;

__global__ void hgnn_init_out(const float4* __restrict__ x4,
                              float4* __restrict__ out4, int n4) {
    int i = blockIdx.x * blockDim.x + threadIdx.x;
    int stride = gridDim.x * blockDim.x;
    for (; i < n4; i += stride) {
        out4[i] = x4[i];
    }
}

__global__ void hgnn_scatter_add(const float4* __restrict__ x4,
                                 const int* __restrict__ src,
                                 const int* __restrict__ dst,
                                 float* __restrict__ out,
                                 long long nitems) {
    long long i = (long long)blockIdx.x * blockDim.x + threadIdx.x;
    long long stride = (long long)gridDim.x * blockDim.x;
    for (; i < nitems; i += stride) {
        long long e = i >> 5;          // edge id
        int q = (int)(i & 31);         // float4 quad within the 128-d row
        int s = src[e];
        int t = dst[e];
        float4 v = x4[(long long)s * (DIM / 4) + q];
        float* o = out + (long long)t * DIM + q * 4;
        atomicAdd(o + 0, v.x);
        atomicAdd(o + 1, v.y);
        atomicAdd(o + 2, v.z);
        atomicAdd(o + 3, v.w);
    }
}

extern "C" void kernel_launch(void* const* d_in, const int* in_sizes, int n_in,
                              void* d_out, int out_size, void* d_ws, size_t ws_size,
                              hipStream_t stream) {
    const float* x = (const float*)d_in[0];
    const int* src = (const int*)d_in[1];
    const int* dst = (const int*)d_in[2];
    float* out = (float*)d_out;

    const long long E = in_sizes[1];          // 2,000,000
    const int n4 = N_NODES * (DIM / 4);       // 3.2M float4s

    // 1) out = x  (fully overwrites the poisoned output buffer)
    {
        int block = 256;
        int grid = 2048;
        hipLaunchKernelGGL(hgnn_init_out, dim3(grid), dim3(block), 0, stream,
                           (const float4*)x, (float4*)out, n4);
    }

    // 2) scatter-add the gathered rows
    {
        long long nitems = E * (DIM / 4);     // 64M work items
        int block = 256;
        int grid = 8192;                      // grid-stride, ~31 iters/thread
        hipLaunchKernelGGL(hgnn_scatter_add, dim3(grid), dim3(block), 0, stream,
                           (const float4*)x, src, dst, out, nitems);
    }
}

// Round 3
// 414.333 us; speedup vs baseline: 8.1028x; 8.1028x over previous
//
#include <hip/hip_runtime.h>

// HGNN aggregation: out = x + segment_sum(x[src_idx], dst_idx)
// x: [100000, 128] f32; src_idx/dst_idx: [2,000,000] int32.
//
// Round 3: CSR-build + gather. No f32 atomics.
//   1. counts[t]  = #members per target      (2M int atomics)
//   2. offsets    = exclusive_scan(counts)   (3 tiny kernels)
//   3. csr[...]   = src ids grouped by dst   (2M int atomics on cursors)
//   4. aggregate: one wave per node, out = x[node] + sum(x[csr[...]])

constexpr int DIM = 128;
constexpr int CHUNK = 1024;          // elements per scan block (256 thr x 4)

__global__ void hgnn_count(const int* __restrict__ dst, int* __restrict__ counts,
                           int nedges) {
    int i = blockIdx.x * blockDim.x + threadIdx.x;
    int stride = gridDim.x * blockDim.x;
    for (; i < nedges; i += stride) {
        atomicAdd(&counts[dst[i]], 1);
    }
}

__global__ void hgnn_block_reduce(const int* __restrict__ counts,
                                  int* __restrict__ blockSums, int n) {
    __shared__ int s[256];
    int b = blockIdx.x, t = threadIdx.x;
    int base = b * CHUNK + t * 4;
    int sum = 0;
#pragma unroll
    for (int k = 0; k < 4; ++k)
        if (base + k < n) sum += counts[base + k];
    s[t] = sum;
    __syncthreads();
    for (int off = 128; off > 0; off >>= 1) {
        if (t < off) s[t] += s[t + off];
        __syncthreads();
    }
    if (t == 0) blockSums[b] = s[0];
}

// single block, nb <= 128: exclusive-scan blockSums -> blockBase, total -> offsets[n]
__global__ void hgnn_scan_sums(const int* __restrict__ blockSums,
                               int* __restrict__ blockBase,
                               int nb, int* __restrict__ offsets, int n) {
    __shared__ int s[128];
    int t = threadIdx.x;
    int v = (t < nb) ? blockSums[t] : 0;
    s[t] = v;
    __syncthreads();
    for (int off = 1; off < 128; off <<= 1) {
        int val = (t >= off) ? s[t - off] : 0;
        __syncthreads();
        s[t] += val;
        __syncthreads();
    }
    if (t < nb) blockBase[t] = s[t] - v;   // exclusive
    if (t == 127) offsets[n] = s[127];     // total == E
}

__global__ void hgnn_scan_write(const int* __restrict__ counts,
                                const int* __restrict__ blockBase,
                                int* __restrict__ offsets,
                                int* __restrict__ cursors, int n) {
    __shared__ int s[256];
    int b = blockIdx.x, t = threadIdx.x;
    int base = b * CHUNK + t * 4;
    int v0 = 0, v1 = 0, v2 = 0, v3 = 0;
    if (base + 0 < n) v0 = counts[base + 0];
    if (base + 1 < n) v1 = counts[base + 1];
    if (base + 2 < n) v2 = counts[base + 2];
    if (base + 3 < n) v3 = counts[base + 3];
    int tsum = v0 + v1 + v2 + v3;
    s[t] = tsum;
    __syncthreads();
    for (int off = 1; off < 256; off <<= 1) {
        int val = (t >= off) ? s[t - off] : 0;
        __syncthreads();
        s[t] += val;
        __syncthreads();
    }
    int excl = s[t] - tsum + blockBase[b];
    int o0 = excl, o1 = o0 + v0, o2 = o1 + v1, o3 = o2 + v2;
    if (base + 0 < n) { offsets[base + 0] = o0; cursors[base + 0] = o0; }
    if (base + 1 < n) { offsets[base + 1] = o1; cursors[base + 1] = o1; }
    if (base + 2 < n) { offsets[base + 2] = o2; cursors[base + 2] = o2; }
    if (base + 3 < n) { offsets[base + 3] = o3; cursors[base + 3] = o3; }
}

__global__ void hgnn_fill(const int* __restrict__ src, const int* __restrict__ dst,
                          int* __restrict__ cursors, int* __restrict__ csr,
                          int nedges) {
    int i = blockIdx.x * blockDim.x + threadIdx.x;
    int stride = gridDim.x * blockDim.x;
    for (; i < nedges; i += stride) {
        int pos = atomicAdd(&cursors[dst[i]], 1);
        csr[pos] = src[i];
    }
}

// one 64-lane wave per node; each lane owns one float2 of the 128-d row
__global__ void hgnn_aggregate(const float2* __restrict__ x2,
                               const int* __restrict__ csr,
                               const int* __restrict__ offsets,
                               float2* __restrict__ out2, int nnodes) {
    int gtid = blockIdx.x * blockDim.x + threadIdx.x;
    int node = gtid >> 6;
    int lane = threadIdx.x & 63;
    if (node >= nnodes) return;

    int beg = offsets[node];
    int end = offsets[node + 1];

    float2 acc = x2[(long long)node * 64 + lane];   // residual

    int j = beg;
    // 2-deep unroll for memory-level parallelism
    for (; j + 1 < end; j += 2) {
        int m0 = csr[j];
        int m1 = csr[j + 1];
        float2 v0 = x2[(long long)m0 * 64 + lane];
        float2 v1 = x2[(long long)m1 * 64 + lane];
        acc.x += v0.x + v1.x;
        acc.y += v0.y + v1.y;
    }
    if (j < end) {
        int m = csr[j];
        float2 v = x2[(long long)m * 64 + lane];
        acc.x += v.x;
        acc.y += v.y;
    }
    out2[(long long)node * 64 + lane] = acc;
}

extern "C" void kernel_launch(void* const* d_in, const int* in_sizes, int n_in,
                              void* d_out, int out_size, void* d_ws, size_t ws_size,
                              hipStream_t stream) {
    const float* x = (const float*)d_in[0];
    const int* src = (const int*)d_in[1];
    const int* dst = (const int*)d_in[2];
    float* out = (float*)d_out;

    const int E = in_sizes[1];            // 2,000,000
    const int N = in_sizes[0] / DIM;      // 100,000
    const int NB = (N + CHUNK - 1) / CHUNK;  // 98 scan blocks

    // workspace layout (ints)
    int* ws = (int*)d_ws;
    int* counts    = ws;                  // [N]
    int* offsets   = counts + N;          // [N+1]
    int* cursors   = offsets + (N + 1);   // [N]
    int* blockSums = cursors + N;         // [128]
    int* blockBase = blockSums + 128;     // [128]
    int* csr       = blockBase + 128;     // [E]

    // 1) zero counts
    hipMemsetAsync(counts, 0, (size_t)N * sizeof(int), stream);

    // 2) histogram of dst
    hipLaunchKernelGGL(hgnn_count, dim3(2048), dim3(256), 0, stream,
                       dst, counts, E);

    // 3) exclusive scan -> offsets, cursors
    hipLaunchKernelGGL(hgnn_block_reduce, dim3(NB), dim3(256), 0, stream,
                       counts, blockSums, N);
    hipLaunchKernelGGL(hgnn_scan_sums, dim3(1), dim3(128), 0, stream,
                       blockSums, blockBase, NB, offsets, N);
    hipLaunchKernelGGL(hgnn_scan_write, dim3(NB), dim3(256), 0, stream,
                       counts, blockBase, offsets, cursors, N);

    // 4) fill CSR member lists
    hipLaunchKernelGGL(hgnn_fill, dim3(2048), dim3(256), 0, stream,
                       src, dst, cursors, csr, E);

    // 5) gather-aggregate: out = x + sum of member rows
    {
        int wavesPerBlock = 4;                       // 256 threads
        int grid = (N + wavesPerBlock - 1) / wavesPerBlock;
        hipLaunchKernelGGL(hgnn_aggregate, dim3(grid), dim3(256), 0, stream,
                           (const float2*)x, csr, offsets, (float2*)out, N);
    }
}